// Round 1
// baseline (307.978 us; speedup 1.0000x reference)
//
#include <hip/hip_runtime.h>

#define PREFAC_F 138.93544539709032f
#define CUT2 (0.9f * 0.9f)

// ---------------------------------------------------------------------------
// Pack kernel: atom -> float4{x,y,z,q} and float2{sigma,eps} for single-load
// gathers in the pair kernel. Runs every launch (ws is re-poisoned).
// ---------------------------------------------------------------------------
__global__ __launch_bounds__(256) void pack_kernel(
    const float* __restrict__ coords,
    const float* __restrict__ charges,
    const float* __restrict__ sigma,
    const float* __restrict__ epsilon,
    float4* __restrict__ atom,
    float2* __restrict__ se,
    int n)
{
    int i = blockIdx.x * blockDim.x + threadIdx.x;
    if (i < n) {
        float x = coords[3 * i + 0];
        float y = coords[3 * i + 1];
        float z = coords[3 * i + 2];
        atom[i] = make_float4(x, y, z, charges[i]);
        se[i]   = make_float2(sigma[i], epsilon[i]);
    }
}

// ---------------------------------------------------------------------------
// Per-pair energy. valid branch: ~0.3% of pairs pass the cutoff, so most
// wave-iterations skip the se[] gathers + rsqrt/sqrt entirely (execz skip).
// Note: i==j implies i/3==j/3, so the reference's (i != j) test is redundant.
// ---------------------------------------------------------------------------
__device__ __forceinline__ float pair_e(
    int i, int j,
    const float4* __restrict__ atom,
    const float2* __restrict__ se,
    float Lx, float Ly, float Lz,
    float iLx, float iLy, float iLz)
{
    float4 ai = atom[i];
    float4 aj = atom[j];
    float dx = ai.x - aj.x;
    float dy = ai.y - aj.y;
    float dz = ai.z - aj.z;
    dx -= Lx * rintf(dx * iLx);   // jnp.round = round-half-even = rintf
    dy -= Ly * rintf(dy * iLy);
    dz -= Lz * rintf(dz * iLz);
    float r2 = dx * dx + dy * dy + dz * dz;
    bool valid = ((i / 3) != (j / 3)) && (r2 < CUT2);
    float e = 0.0f;
    if (valid) {
        float2 si = se[i];
        float2 sj = se[j];
        float inv_r  = rsqrtf(r2);
        float inv_r2 = inv_r * inv_r;
        float ec = PREFAC_F * ai.w * aj.w * inv_r;
        float sg = 0.5f * (si.x + sj.x);
        float ep = sqrtf(si.y * sj.y);
        float sr2 = sg * sg * inv_r2;
        float sr6 = sr2 * sr2 * sr2;
        e = ec + 4.0f * ep * (sr6 * sr6 - sr6);
    }
    return e;
}

// ---------------------------------------------------------------------------
// Main pair kernel: grid-stride over groups of 4 pairs (2x int4 coalesced
// loads = 32B/lane of the 128MB pair stream). Wave reduce -> LDS -> one
// float atomicAdd per block.
// ---------------------------------------------------------------------------
__global__ __launch_bounds__(256) void pair_kernel(
    const int4* __restrict__ p4, int ngroups,
    const float4* __restrict__ atom,
    const float2* __restrict__ se,
    const float* __restrict__ box,
    float* __restrict__ out,
    int tail_base, int tail_count,
    const int* __restrict__ pairs_flat)
{
    float Lx = box[0], Ly = box[4], Lz = box[8];
    float iLx = 1.0f / Lx, iLy = 1.0f / Ly, iLz = 1.0f / Lz;

    float acc = 0.0f;
    int tid    = blockIdx.x * blockDim.x + threadIdx.x;
    int stride = gridDim.x * blockDim.x;

    for (int g = tid; g < ngroups; g += stride) {
        int4 a = p4[2 * g + 0];
        int4 b = p4[2 * g + 1];
        acc += pair_e(a.x, a.y, atom, se, Lx, Ly, Lz, iLx, iLy, iLz);
        acc += pair_e(a.z, a.w, atom, se, Lx, Ly, Lz, iLx, iLy, iLz);
        acc += pair_e(b.x, b.y, atom, se, Lx, Ly, Lz, iLx, iLy, iLz);
        acc += pair_e(b.z, b.w, atom, se, Lx, Ly, Lz, iLx, iLy, iLz);
    }

    // leftover pairs (none when n_pairs % 4 == 0, but be safe)
    if (tid < tail_count) {
        int i = pairs_flat[2 * (tail_base + tid) + 0];
        int j = pairs_flat[2 * (tail_base + tid) + 1];
        acc += pair_e(i, j, atom, se, Lx, Ly, Lz, iLx, iLy, iLz);
    }

    // wave64 reduction
    #pragma unroll
    for (int off = 32; off > 0; off >>= 1)
        acc += __shfl_down(acc, off, 64);

    __shared__ float wsum[4];  // 256 threads / 64 = 4 waves
    int lane = threadIdx.x & 63;
    int wid  = threadIdx.x >> 6;
    if (lane == 0) wsum[wid] = acc;
    __syncthreads();
    if (threadIdx.x == 0)
        atomicAdd(out, wsum[0] + wsum[1] + wsum[2] + wsum[3]);
}

extern "C" void kernel_launch(void* const* d_in, const int* in_sizes, int n_in,
                              void* d_out, int out_size, void* d_ws, size_t ws_size,
                              hipStream_t stream)
{
    const float* coords  = (const float*)d_in[0];
    const float* box     = (const float*)d_in[1];
    const float* charges = (const float*)d_in[2];
    const float* sigma   = (const float*)d_in[3];
    const float* epsilon = (const float*)d_in[4];
    const int*   pairs   = (const int*)d_in[5];

    int  n_atoms = in_sizes[2];
    long n_pairs = (long)in_sizes[5] / 2;

    // ws layout: [float4 atom packed][float2 sigma/eps packed]
    float4* atom = (float4*)d_ws;
    size_t  atom_bytes = ((size_t)n_atoms * sizeof(float4) + 255) & ~(size_t)255;
    float2* se = (float2*)((char*)d_ws + atom_bytes);

    hipMemsetAsync(d_out, 0, sizeof(float), stream);

    pack_kernel<<<(n_atoms + 255) / 256, 256, 0, stream>>>(
        coords, charges, sigma, epsilon, atom, se, n_atoms);

    int ngroups    = (int)(n_pairs / 4);
    int tail_base  = ngroups * 4;
    int tail_count = (int)(n_pairs - (long)tail_base);

    int blocks = 2048;
    pair_kernel<<<blocks, 256, 0, stream>>>(
        (const int4*)pairs, ngroups, atom, se, box, (float*)d_out,
        tail_base, tail_count, pairs);
}